// Round 6
// baseline (7711.088 us; speedup 1.0000x reference)
//
#include <hip/hip_runtime.h>

#define EMB 64
#define TILE 64      // edges/nodes per block-tile
#define KCH 32       // K chunk staged in LDS
#define THREADS 256
#define AROW (TILE + 4)   // padded row for transposed tiles (68 floats, 16B-aligned rows)

__device__ __forceinline__ float reluf(float v) { return fmaxf(v, 0.0f); }

__device__ __forceinline__ float f4c(const float4& v, int i) {
    return i == 0 ? v.x : (i == 1 ? v.y : (i == 2 ? v.z : v.w));
}

// ---------------------------------------------------------------- lin_in ----
__global__ __launch_bounds__(THREADS) void lin_in_kernel(
    const float* __restrict__ x, const float* __restrict__ w,
    const float* __restrict__ b, float* __restrict__ h, int N)
{
    int idx = blockIdx.x * blockDim.x + threadIdx.x;
    if (idx >= N * EMB) return;
    int n = idx >> 6, j = idx & 63;
    float s = b[j];
#pragma unroll
    for (int k = 0; k < 5; ++k) s += x[n * 5 + k] * w[k * EMB + j];
    h[idx] = s;
}

// ------------------------------------------------- fused edge message MLP ----
// Per edge e: m = relu(relu(cat(h[dst],h[src],dist) @ w1 + b1) @ w2 + b2)
// then atomicAdd into aggr[dst].
// Block: 256 threads, tile of 64 edges. Thread computes 4 edges x 4 features.
__global__ __launch_bounds__(THREADS, 2) void edge_msg_kernel(
    const float* __restrict__ h, const float* __restrict__ dists,
    const int* __restrict__ src, const int* __restrict__ dst,
    const float* __restrict__ w1, const float* __restrict__ b1,
    const float* __restrict__ w2, const float* __restrict__ b2,
    float* __restrict__ aggr, int nE)
{
    __shared__ __align__(16) float w1s[128][EMB];   // rows 0..63 dst-part, 64..127 src-part
    __shared__ __align__(16) float w2s[EMB][EMB];
    __shared__ __align__(16) float w1d[EMB];        // dist row (k=128)
    __shared__ __align__(16) float b1s[EMB];
    __shared__ __align__(16) float b2s[EMB];
    __shared__ __align__(16) float At[KCH][AROW];   // cat chunk, transposed [k][edge]
    __shared__ __align__(16) float m1t[EMB][AROW];  // hidden, transposed [k][edge]
    __shared__ int   dsts[TILE];
    __shared__ int   srcs[TILE];
    __shared__ __align__(16) float dts[TILE];

    const int tid = threadIdx.x;
    for (int i = tid; i < 128 * EMB; i += THREADS) w1s[i >> 6][i & 63] = w1[i];
    for (int i = tid; i < EMB * EMB; i += THREADS) w2s[i >> 6][i & 63] = w2[i];
    if (tid < EMB) {
        w1d[tid] = w1[128 * EMB + tid];
        b1s[tid] = b1[tid];
        b2s[tid] = b2[tid];
    }
    __syncthreads();

    const int eg = tid & 15;   // edge group  -> edges e0..e0+3
    const int fg = tid >> 4;   // feature grp -> feats j0..j0+3
    const int e0 = eg * 4;
    const int j0 = fg * 4;

    for (int t0 = blockIdx.x * TILE; t0 < nE; t0 += gridDim.x * TILE) {
        __syncthreads();  // protect dsts/srcs/dts/m1t from previous iteration readers
        if (tid < TILE) {
            int e = t0 + tid;
            bool v = e < nE;
            dsts[tid] = v ? dst[e] : 0;
            srcs[tid] = v ? src[e] : 0;
            dts[tid]  = v ? dists[e] : 0.0f;
        }

        float4 acc[4];
#pragma unroll
        for (int ji = 0; ji < 4; ++ji) {
            float bv = b1s[j0 + ji];
            acc[ji] = make_float4(bv, bv, bv, bv);
        }

        // GEMM1: K = 128 in 4 chunks of 32 (chunks 0,1 from h[dst], 2,3 from h[src])
#pragma unroll
        for (int c = 0; c < 4; ++c) {
            __syncthreads();
            {
                const int* idxp = (c < 2) ? dsts : srcs;
                const int koff = (c & 1) * 32;
                const int e = tid >> 2;
                const int kk0 = (tid & 3) * 8;
                const int row = idxp[e];
                const float* p = h + (size_t)row * EMB + koff + kk0;
                float4 v0 = *(const float4*)p;
                float4 v1 = *(const float4*)(p + 4);
                At[kk0 + 0][e] = v0.x; At[kk0 + 1][e] = v0.y;
                At[kk0 + 2][e] = v0.z; At[kk0 + 3][e] = v0.w;
                At[kk0 + 4][e] = v1.x; At[kk0 + 5][e] = v1.y;
                At[kk0 + 6][e] = v1.z; At[kk0 + 7][e] = v1.w;
            }
            __syncthreads();
#pragma unroll
            for (int kk = 0; kk < KCH; ++kk) {
                float4 a = *(const float4*)&At[kk][e0];
                float4 w = *(const float4*)&w1s[c * 32 + kk][j0];
                acc[0].x += a.x * w.x; acc[0].y += a.y * w.x; acc[0].z += a.z * w.x; acc[0].w += a.w * w.x;
                acc[1].x += a.x * w.y; acc[1].y += a.y * w.y; acc[1].z += a.z * w.y; acc[1].w += a.w * w.y;
                acc[2].x += a.x * w.z; acc[2].y += a.y * w.z; acc[2].z += a.z * w.z; acc[2].w += a.w * w.z;
                acc[3].x += a.x * w.w; acc[3].y += a.y * w.w; acc[3].z += a.z * w.w; acc[3].w += a.w * w.w;
            }
        }

        // dist term (k = 128) + ReLU, write hidden transposed
        {
            float4 dv = *(const float4*)&dts[e0];
#pragma unroll
            for (int ji = 0; ji < 4; ++ji) {
                float wd = w1d[j0 + ji];
                float4 r;
                r.x = reluf(acc[ji].x + dv.x * wd);
                r.y = reluf(acc[ji].y + dv.y * wd);
                r.z = reluf(acc[ji].z + dv.z * wd);
                r.w = reluf(acc[ji].w + dv.w * wd);
                *(float4*)&m1t[j0 + ji][e0] = r;
            }
        }
        __syncthreads();

        // GEMM2: K = 64
        float4 o[4];
#pragma unroll
        for (int ji = 0; ji < 4; ++ji) {
            float bv = b2s[j0 + ji];
            o[ji] = make_float4(bv, bv, bv, bv);
        }
#pragma unroll 16
        for (int k = 0; k < EMB; ++k) {
            float4 a = *(const float4*)&m1t[k][e0];
            float4 w = *(const float4*)&w2s[k][j0];
            o[0].x += a.x * w.x; o[0].y += a.y * w.x; o[0].z += a.z * w.x; o[0].w += a.w * w.x;
            o[1].x += a.x * w.y; o[1].y += a.y * w.y; o[1].z += a.z * w.y; o[1].w += a.w * w.y;
            o[2].x += a.x * w.z; o[2].y += a.y * w.z; o[2].z += a.z * w.z; o[2].w += a.w * w.z;
            o[3].x += a.x * w.w; o[3].y += a.y * w.w; o[3].z += a.z * w.w; o[3].w += a.w * w.w;
        }

        // ReLU + scatter-add
#pragma unroll
        for (int ei = 0; ei < 4; ++ei) {
            int e = t0 + e0 + ei;
            if (e < nE) {
                int base = dsts[e0 + ei] * EMB + j0;
#pragma unroll
                for (int ji = 0; ji < 4; ++ji)
                    atomicAdd(&aggr[base + ji], reluf(f4c(o[ji], ei)));
            }
        }
    }
}

// ------------------------------------------------------ fused node update ----
// u = relu(relu(cat(h, aggr) @ w1 + b1) @ w2 + b2); h += u
// Also re-zeroes aggr rows after their last read, so the next layer's edge
// kernel starts from a clean accumulator without a separate memset.
__global__ __launch_bounds__(THREADS, 2) void node_upd_kernel(
    float* __restrict__ h, float* __restrict__ aggr,
    const float* __restrict__ w1, const float* __restrict__ b1,
    const float* __restrict__ w2, const float* __restrict__ b2, int N)
{
    __shared__ __align__(16) float w1s[128][EMB];
    __shared__ __align__(16) float w2s[EMB][EMB];
    __shared__ __align__(16) float b1s[EMB];
    __shared__ __align__(16) float b2s[EMB];
    __shared__ __align__(16) float At[KCH][AROW];
    __shared__ __align__(16) float m1t[EMB][AROW];

    const int tid = threadIdx.x;
    for (int i = tid; i < 128 * EMB; i += THREADS) w1s[i >> 6][i & 63] = w1[i];
    for (int i = tid; i < EMB * EMB; i += THREADS) w2s[i >> 6][i & 63] = w2[i];
    if (tid < EMB) { b1s[tid] = b1[tid]; b2s[tid] = b2[tid]; }
    __syncthreads();

    const int eg = tid & 15;
    const int fg = tid >> 4;
    const int e0 = eg * 4;
    const int j0 = fg * 4;

    for (int t0 = blockIdx.x * TILE; t0 < N; t0 += gridDim.x * TILE) {
        float4 acc[4];
#pragma unroll
        for (int ji = 0; ji < 4; ++ji) {
            float bv = b1s[j0 + ji];
            acc[ji] = make_float4(bv, bv, bv, bv);
        }

#pragma unroll
        for (int c = 0; c < 4; ++c) {
            __syncthreads();
            {
                const float* base = (c < 2) ? h : aggr;
                const int koff = (c & 1) * 32;
                const int e = tid >> 2;
                const int kk0 = (tid & 3) * 8;
                const int n = t0 + e;
                float4 v0 = make_float4(0.f, 0.f, 0.f, 0.f), v1 = v0;
                if (n < N) {
                    const float* p = base + (size_t)n * EMB + koff + kk0;
                    v0 = *(const float4*)p;
                    v1 = *(const float4*)(p + 4);
                }
                At[kk0 + 0][e] = v0.x; At[kk0 + 1][e] = v0.y;
                At[kk0 + 2][e] = v0.z; At[kk0 + 3][e] = v0.w;
                At[kk0 + 4][e] = v1.x; At[kk0 + 5][e] = v1.y;
                At[kk0 + 6][e] = v1.z; At[kk0 + 7][e] = v1.w;
            }
            __syncthreads();
#pragma unroll
            for (int kk = 0; kk < KCH; ++kk) {
                float4 a = *(const float4*)&At[kk][e0];
                float4 w = *(const float4*)&w1s[c * 32 + kk][j0];
                acc[0].x += a.x * w.x; acc[0].y += a.y * w.x; acc[0].z += a.z * w.x; acc[0].w += a.w * w.x;
                acc[1].x += a.x * w.y; acc[1].y += a.y * w.y; acc[1].z += a.z * w.y; acc[1].w += a.w * w.y;
                acc[2].x += a.x * w.z; acc[2].y += a.y * w.z; acc[2].z += a.z * w.z; acc[2].w += a.w * w.z;
                acc[3].x += a.x * w.w; acc[3].y += a.y * w.w; acc[3].z += a.z * w.w; acc[3].w += a.w * w.w;
            }
        }

#pragma unroll
        for (int ji = 0; ji < 4; ++ji) {
            float4 r;
            r.x = reluf(acc[ji].x); r.y = reluf(acc[ji].y);
            r.z = reluf(acc[ji].z); r.w = reluf(acc[ji].w);
            *(float4*)&m1t[j0 + ji][e0] = r;
        }
        __syncthreads();

        float4 o[4];
#pragma unroll
        for (int ji = 0; ji < 4; ++ji) {
            float bv = b2s[j0 + ji];
            o[ji] = make_float4(bv, bv, bv, bv);
        }
#pragma unroll 16
        for (int k = 0; k < EMB; ++k) {
            float4 a = *(const float4*)&m1t[k][e0];
            float4 w = *(const float4*)&w2s[k][j0];
            o[0].x += a.x * w.x; o[0].y += a.y * w.x; o[0].z += a.z * w.x; o[0].w += a.w * w.x;
            o[1].x += a.x * w.y; o[1].y += a.y * w.y; o[1].z += a.z * w.y; o[1].w += a.w * w.y;
            o[2].x += a.x * w.z; o[2].y += a.y * w.z; o[2].z += a.z * w.z; o[2].w += a.w * w.z;
            o[3].x += a.x * w.w; o[3].y += a.y * w.w; o[3].z += a.z * w.w; o[3].w += a.w * w.w;
        }

        // residual add: h[n][j0..j0+3] += relu(u2)
#pragma unroll
        for (int ei = 0; ei < 4; ++ei) {
            int n = t0 + e0 + ei;
            if (n < N) {
                float4* hp = (float4*)&h[(size_t)n * EMB + j0];
                float4 cur = *hp;
                cur.x += reluf(f4c(o[0], ei));
                cur.y += reluf(f4c(o[1], ei));
                cur.z += reluf(f4c(o[2], ei));
                cur.w += reluf(f4c(o[3], ei));
                *hp = cur;
            }
        }

        // re-zero this tile's aggr rows (last read was in staging chunks c=2,3;
        // only this block touches rows [t0, t0+TILE) — no cross-block hazard)
        {
            const int zr = t0 + (tid >> 2);
            if (zr < N) {
                float4 z = make_float4(0.f, 0.f, 0.f, 0.f);
                float4* zp = (float4*)&aggr[(size_t)zr * EMB + (tid & 3) * 16];
                zp[0] = z; zp[1] = z; zp[2] = z; zp[3] = z;
            }
        }
        __syncthreads();  // m1t/At reuse safety for next tile
    }
}

// --------------------------------------------------------------- pooling ----
__global__ __launch_bounds__(256) void pool_kernel(
    const float* __restrict__ h, float* __restrict__ pool, int N)
{
    __shared__ float red[4][EMB];
    const int lane = threadIdx.x & 63;
    const int wv = threadIdx.x >> 6;
    float s = 0.0f;
    for (int n = blockIdx.x * 4 + wv; n < N; n += gridDim.x * 4)
        s += h[(size_t)n * EMB + lane];
    red[wv][lane] = s;
    __syncthreads();
    if (threadIdx.x < EMB) {
        float t = red[0][threadIdx.x] + red[1][threadIdx.x] +
                  red[2][threadIdx.x] + red[3][threadIdx.x];
        atomicAdd(&pool[threadIdx.x], t);
    }
}

__global__ void final_kernel(const float* __restrict__ pool,
                             const float* __restrict__ pw,
                             const float* __restrict__ pb,
                             float* __restrict__ out, int N)
{
    int j = threadIdx.x;  // 64 threads
    float v = (pool[j] / (float)N) * pw[j];
#pragma unroll
    for (int off = 32; off; off >>= 1) v += __shfl_down(v, off, 64);
    if (j == 0) out[0] = v + pb[0];
}

// ---------------------------------------------------------------- launch ----
extern "C" void kernel_launch(void* const* d_in, const int* in_sizes, int n_in,
                              void* d_out, int out_size, void* d_ws, size_t ws_size,
                              hipStream_t stream)
{
    const float* x     = (const float*)d_in[0];
    const float* dists = (const float*)d_in[1];
    const int*   ei    = (const int*)d_in[2];
    // d_in[3] = batch (all zeros, unused: single graph mean pool)
    const float* lw  = (const float*)d_in[4];
    const float* lb  = (const float*)d_in[5];
    const float* mw1 = (const float*)d_in[6];
    const float* mb1 = (const float*)d_in[7];
    const float* mw2 = (const float*)d_in[8];
    const float* mb2 = (const float*)d_in[9];
    const float* uw1 = (const float*)d_in[10];
    const float* ub1 = (const float*)d_in[11];
    const float* uw2 = (const float*)d_in[12];
    const float* ub2 = (const float*)d_in[13];
    const float* pw  = (const float*)d_in[14];
    const float* pb  = (const float*)d_in[15];

    const int N = in_sizes[0] / 5;
    const int E = in_sizes[2] / 2;
    const int* src = ei;        // edge_index[0]
    const int* dst = ei + E;    // edge_index[1]

    // Workspace layout: h [N*EMB] | aggr [N*EMB] | pool [EMB]
    const size_t need = ((size_t)N * EMB * 2 + EMB) * sizeof(float);
    if (ws_size < need) {
        // Defensive: never scribble past d_ws. (Result will be wrong, but the
        // harness reports a clean mismatch instead of the container dying.)
        return;
    }

    float* h    = (float*)d_ws;
    float* aggr = h + (size_t)N * EMB;
    float* pool = aggr + (size_t)N * EMB;

    lin_in_kernel<<<(N * EMB + THREADS - 1) / THREADS, THREADS, 0, stream>>>(x, lw, lb, h, N);

    // 2 blocks/CU (LDS-limited) x 256 CUs = 512 co-resident blocks: launch
    // exactly that many and grid-stride, so weights are staged once per block.
    int egrid = 512;
    int etiles = (E + TILE - 1) / TILE;
    if (etiles < egrid) egrid = etiles;
    int ugrid = 512;
    int utiles = (N + TILE - 1) / TILE;
    if (utiles < ugrid) ugrid = utiles;

    // aggr must start zeroed (ws is poisoned 0xAA before every launch);
    // node_upd_kernel re-zeroes it for subsequent layers.
    hipMemsetAsync(aggr, 0, (size_t)N * EMB * sizeof(float), stream);

    for (int l = 0; l < 4; ++l) {
        edge_msg_kernel<<<egrid, THREADS, 0, stream>>>(
            h, dists, src, dst,
            mw1 + (size_t)l * 129 * EMB, mb1 + l * EMB,
            mw2 + (size_t)l * EMB * EMB, mb2 + l * EMB,
            aggr, E);
        node_upd_kernel<<<ugrid, THREADS, 0, stream>>>(
            h, aggr,
            uw1 + (size_t)l * 128 * EMB, ub1 + l * EMB,
            uw2 + (size_t)l * EMB * EMB, ub2 + l * EMB, N);
    }

    hipMemsetAsync(pool, 0, EMB * sizeof(float), stream);
    pool_kernel<<<256, 256, 0, stream>>>(h, pool, N);
    final_kernel<<<1, 64, 0, stream>>>(pool, pw, pb, (float*)d_out, N);
}

// Round 10
// 5744.016 us; speedup vs baseline: 1.3425x; 1.3425x over previous
//
#include <hip/hip_runtime.h>

#define EMB 64
#define TILE 64      // edges/nodes per block-tile
#define KCH 32       // K chunk staged in LDS
#define THREADS 256
#define AROW (TILE + 4)   // padded row for transposed tiles (68 floats, 16B-aligned rows)
#define SCAN_CHUNK 1024   // scan1: 256 threads x 4 elems

__device__ __forceinline__ float reluf(float v) { return fmaxf(v, 0.0f); }

__device__ __forceinline__ float f4c(const float4& v, int i) {
    return i == 0 ? v.x : (i == 1 ? v.y : (i == 2 ? v.z : v.w));
}

// ---------------------------------------------------------------- lin_in ----
__global__ __launch_bounds__(THREADS) void lin_in_kernel(
    const float* __restrict__ x, const float* __restrict__ w,
    const float* __restrict__ b, float* __restrict__ h, int N)
{
    int idx = blockIdx.x * blockDim.x + threadIdx.x;
    if (idx >= N * EMB) return;
    int n = idx >> 6, j = idx & 63;
    float s = b[j];
#pragma unroll
    for (int k = 0; k < 5; ++k) s += x[n * 5 + k] * w[k * EMB + j];
    h[idx] = s;
}

// ----------------------------------------------- CSR build: counting sort ----
__global__ __launch_bounds__(256) void hist_kernel(
    const int* __restrict__ dst, int* __restrict__ cnt, int E)
{
    for (int e = blockIdx.x * blockDim.x + threadIdx.x; e < E;
         e += gridDim.x * blockDim.x)
        atomicAdd(&cnt[dst[e]], 1);
}

// exclusive scan, level 1: per-1024 chunk (256 thr x 4), writes chunk-local
// exclusive into excl[] and chunk totals into bsum[]
__global__ __launch_bounds__(256) void scan1_kernel(
    const int* __restrict__ cnt, int* __restrict__ excl,
    int* __restrict__ bsum, int N)
{
    __shared__ int s[256];
    const int t = threadIdx.x;
    const int base = blockIdx.x * SCAN_CHUNK + t * 4;
    int v0 = (base + 0 < N) ? cnt[base + 0] : 0;
    int v1 = (base + 1 < N) ? cnt[base + 1] : 0;
    int v2 = (base + 2 < N) ? cnt[base + 2] : 0;
    int v3 = (base + 3 < N) ? cnt[base + 3] : 0;
    int sum = v0 + v1 + v2 + v3;
    s[t] = sum;
    __syncthreads();
    for (int d = 1; d < 256; d <<= 1) {
        int x = (t >= d) ? s[t - d] : 0;
        __syncthreads();
        s[t] += x;
        __syncthreads();
    }
    int excl_t = s[t] - sum;
    if (t == 255) bsum[blockIdx.x] = s[255];
    if (base + 0 < N) excl[base + 0] = excl_t;
    if (base + 1 < N) excl[base + 1] = excl_t + v0;
    if (base + 2 < N) excl[base + 2] = excl_t + v0 + v1;
    if (base + 3 < N) excl[base + 3] = excl_t + v0 + v1 + v2;
}

// level 2: exclusive scan of the (<=256) chunk totals, in place
__global__ __launch_bounds__(256) void scan2_kernel(int* __restrict__ bsum, int nb)
{
    __shared__ int s[256];
    const int t = threadIdx.x;
    int orig = (t < nb) ? bsum[t] : 0;
    s[t] = orig;
    __syncthreads();
    for (int d = 1; d < 256; d <<= 1) {
        int x = (t >= d) ? s[t - d] : 0;
        __syncthreads();
        s[t] += x;
        __syncthreads();
    }
    if (t < nb) bsum[t] = s[t] - orig;
}

// level 3: add chunk offsets
__global__ __launch_bounds__(256) void scan3_kernel(
    int* __restrict__ excl, const int* __restrict__ bsum, int N)
{
    for (int i = blockIdx.x * blockDim.x + threadIdx.x; i < N;
         i += gridDim.x * blockDim.x)
        excl[i] += bsum[i >> 10];   // i / SCAN_CHUNK
}

// scatter edge ids into dst-sorted order (cursor starts at row starts)
__global__ __launch_bounds__(256) void scatter_kernel(
    const int* __restrict__ dst, int* __restrict__ cursor,
    int* __restrict__ perm, int E)
{
    for (int e = blockIdx.x * blockDim.x + threadIdx.x; e < E;
         e += gridDim.x * blockDim.x) {
        int p = atomicAdd(&cursor[dst[e]], 1);
        perm[p] = e;
    }
}

// ------------------------------------------------- fused edge message MLP ----
// Processes edges in dst-sorted order (via perm). After the MLP, messages are
// reduced per dst-run with an in-wave segmented scan; only run tails emit
// atomics (~12x fewer atomics and ~12x less RMW write traffic than per-edge).
__global__ __launch_bounds__(THREADS, 2) void edge_msg_kernel(
    const float* __restrict__ h, const float* __restrict__ dists,
    const int* __restrict__ src, const int* __restrict__ dst,
    const int* __restrict__ perm,
    const float* __restrict__ w1, const float* __restrict__ b1,
    const float* __restrict__ w2, const float* __restrict__ b2,
    float* __restrict__ aggr, int nE)
{
    __shared__ __align__(16) float w1s[128][EMB];   // rows 0..63 dst-part, 64..127 src-part
    __shared__ __align__(16) float w2s[EMB][EMB];
    __shared__ __align__(16) float w1d[EMB];        // dist row (k=128)
    __shared__ __align__(16) float b1s[EMB];
    __shared__ __align__(16) float b2s[EMB];
    __shared__ __align__(16) float At[KCH][AROW];   // cat chunk, transposed [k][edge]
    __shared__ __align__(16) float m1t[EMB][AROW];  // hidden / message, transposed [k][edge]
    __shared__ int   dsts[TILE];
    __shared__ int   srcs[TILE];
    __shared__ __align__(16) float dts[TILE];

    const int tid = threadIdx.x;
    for (int i = tid; i < 128 * EMB; i += THREADS) w1s[i >> 6][i & 63] = w1[i];
    for (int i = tid; i < EMB * EMB; i += THREADS) w2s[i >> 6][i & 63] = w2[i];
    if (tid < EMB) {
        w1d[tid] = w1[128 * EMB + tid];
        b1s[tid] = b1[tid];
        b2s[tid] = b2[tid];
    }
    __syncthreads();

    const int eg = tid & 15;   // edge group  -> edges e0..e0+3
    const int fg = tid >> 4;   // feature grp -> feats j0..j0+3
    const int e0 = eg * 4;
    const int j0 = fg * 4;
    const int lane = tid & 63; // for the segmented-scan phase: lane == edge
    const int wv = tid >> 6;   // wave id: owns feats wv*16 .. wv*16+15

    for (int t0 = blockIdx.x * TILE; t0 < nE; t0 += gridDim.x * TILE) {
        __syncthreads();  // protect dsts/srcs/dts/m1t from previous iteration readers
        if (tid < TILE) {
            int e = t0 + tid;
            bool v = e < nE;
            int pe = v ? perm[e] : 0;
            dsts[tid] = v ? dst[pe] : -1;   // -1 pad: merges only with pads, never emitted
            srcs[tid] = v ? src[pe] : 0;
            dts[tid]  = v ? dists[pe] : 0.0f;
        }

        float4 acc[4];
#pragma unroll
        for (int ji = 0; ji < 4; ++ji) {
            float bv = b1s[j0 + ji];
            acc[ji] = make_float4(bv, bv, bv, bv);
        }

        // GEMM1: K = 128 in 4 chunks of 32 (chunks 0,1 from h[dst], 2,3 from h[src])
#pragma unroll
        for (int c = 0; c < 4; ++c) {
            __syncthreads();
            {
                const int* idxp = (c < 2) ? dsts : srcs;
                const int koff = (c & 1) * 32;
                const int e = tid >> 2;
                const int kk0 = (tid & 3) * 8;
                int row = idxp[e];
                if (row < 0) row = 0;       // pad-safe
                const float* p = h + (size_t)row * EMB + koff + kk0;
                float4 v0 = *(const float4*)p;
                float4 v1 = *(const float4*)(p + 4);
                At[kk0 + 0][e] = v0.x; At[kk0 + 1][e] = v0.y;
                At[kk0 + 2][e] = v0.z; At[kk0 + 3][e] = v0.w;
                At[kk0 + 4][e] = v1.x; At[kk0 + 5][e] = v1.y;
                At[kk0 + 6][e] = v1.z; At[kk0 + 7][e] = v1.w;
            }
            __syncthreads();
#pragma unroll
            for (int kk = 0; kk < KCH; ++kk) {
                float4 a = *(const float4*)&At[kk][e0];
                float4 w = *(const float4*)&w1s[c * 32 + kk][j0];
                acc[0].x += a.x * w.x; acc[0].y += a.y * w.x; acc[0].z += a.z * w.x; acc[0].w += a.w * w.x;
                acc[1].x += a.x * w.y; acc[1].y += a.y * w.y; acc[1].z += a.z * w.y; acc[1].w += a.w * w.y;
                acc[2].x += a.x * w.z; acc[2].y += a.y * w.z; acc[2].z += a.z * w.z; acc[2].w += a.w * w.z;
                acc[3].x += a.x * w.w; acc[3].y += a.y * w.w; acc[3].z += a.z * w.w; acc[3].w += a.w * w.w;
            }
        }

        // dist term (k = 128) + ReLU, write hidden transposed
        {
            float4 dv = *(const float4*)&dts[e0];
#pragma unroll
            for (int ji = 0; ji < 4; ++ji) {
                float wd = w1d[j0 + ji];
                float4 r;
                r.x = reluf(acc[ji].x + dv.x * wd);
                r.y = reluf(acc[ji].y + dv.y * wd);
                r.z = reluf(acc[ji].z + dv.z * wd);
                r.w = reluf(acc[ji].w + dv.w * wd);
                *(float4*)&m1t[j0 + ji][e0] = r;
            }
        }
        __syncthreads();

        // GEMM2: K = 64
        float4 o[4];
#pragma unroll
        for (int ji = 0; ji < 4; ++ji) {
            float bv = b2s[j0 + ji];
            o[ji] = make_float4(bv, bv, bv, bv);
        }
#pragma unroll 16
        for (int k = 0; k < EMB; ++k) {
            float4 a = *(const float4*)&m1t[k][e0];
            float4 w = *(const float4*)&w2s[k][j0];
            o[0].x += a.x * w.x; o[0].y += a.y * w.x; o[0].z += a.z * w.x; o[0].w += a.w * w.x;
            o[1].x += a.x * w.y; o[1].y += a.y * w.y; o[1].z += a.z * w.y; o[1].w += a.w * w.y;
            o[2].x += a.x * w.z; o[2].y += a.y * w.z; o[2].z += a.z * w.z; o[2].w += a.w * w.z;
            o[3].x += a.x * w.w; o[3].y += a.y * w.w; o[3].z += a.z * w.w; o[3].w += a.w * w.w;
        }

        // ReLU + transpose messages into m1t[feat][edge] (m1t is free after GEMM2)
        __syncthreads();
#pragma unroll
        for (int ji = 0; ji < 4; ++ji) {
            float4 r;
            r.x = reluf(o[ji].x); r.y = reluf(o[ji].y);
            r.z = reluf(o[ji].z); r.w = reluf(o[ji].w);
            *(float4*)&m1t[j0 + ji][e0] = r;
        }
        __syncthreads();

        // In-wave segmented inclusive scan over the 64 sorted edges (seg = dst).
        // Each wave owns 16 features for all 64 edges.
        {
            const int myd = dsts[lane];
            float val[16];
#pragma unroll
            for (int f = 0; f < 16; ++f) val[f] = m1t[wv * 16 + f][lane];
#pragma unroll
            for (int d = 1; d < 64; d <<= 1) {
                int pd = __shfl_up(myd, d, 64);
                bool add = (lane >= d) && (pd == myd);
#pragma unroll
                for (int f = 0; f < 16; ++f) {
                    float pv = __shfl_up(val[f], d, 64);
                    if (add) val[f] += pv;
                }
            }
            int nd = __shfl_down(myd, 1, 64);
            bool tail = (lane == 63) || (nd != myd);
            if (tail && myd >= 0) {
                float* ap = &aggr[(size_t)myd * EMB + wv * 16];
#pragma unroll
                for (int f = 0; f < 16; ++f) atomicAdd(&ap[f], val[f]);
            }
        }
    }
}

// ------------------------------------------------------ fused node update ----
// u = relu(relu(cat(h, aggr) @ w1 + b1) @ w2 + b2); h += u
// Also re-zeroes aggr rows after their last read, so the next layer's edge
// kernel starts from a clean accumulator without a separate memset.
__global__ __launch_bounds__(THREADS, 2) void node_upd_kernel(
    float* __restrict__ h, float* __restrict__ aggr,
    const float* __restrict__ w1, const float* __restrict__ b1,
    const float* __restrict__ w2, const float* __restrict__ b2, int N)
{
    __shared__ __align__(16) float w1s[128][EMB];
    __shared__ __align__(16) float w2s[EMB][EMB];
    __shared__ __align__(16) float b1s[EMB];
    __shared__ __align__(16) float b2s[EMB];
    __shared__ __align__(16) float At[KCH][AROW];
    __shared__ __align__(16) float m1t[EMB][AROW];

    const int tid = threadIdx.x;
    for (int i = tid; i < 128 * EMB; i += THREADS) w1s[i >> 6][i & 63] = w1[i];
    for (int i = tid; i < EMB * EMB; i += THREADS) w2s[i >> 6][i & 63] = w2[i];
    if (tid < EMB) { b1s[tid] = b1[tid]; b2s[tid] = b2[tid]; }
    __syncthreads();

    const int eg = tid & 15;
    const int fg = tid >> 4;
    const int e0 = eg * 4;
    const int j0 = fg * 4;

    for (int t0 = blockIdx.x * TILE; t0 < N; t0 += gridDim.x * TILE) {
        float4 acc[4];
#pragma unroll
        for (int ji = 0; ji < 4; ++ji) {
            float bv = b1s[j0 + ji];
            acc[ji] = make_float4(bv, bv, bv, bv);
        }

#pragma unroll
        for (int c = 0; c < 4; ++c) {
            __syncthreads();
            {
                const float* base = (c < 2) ? h : aggr;
                const int koff = (c & 1) * 32;
                const int e = tid >> 2;
                const int kk0 = (tid & 3) * 8;
                const int n = t0 + e;
                float4 v0 = make_float4(0.f, 0.f, 0.f, 0.f), v1 = v0;
                if (n < N) {
                    const float* p = base + (size_t)n * EMB + koff + kk0;
                    v0 = *(const float4*)p;
                    v1 = *(const float4*)(p + 4);
                }
                At[kk0 + 0][e] = v0.x; At[kk0 + 1][e] = v0.y;
                At[kk0 + 2][e] = v0.z; At[kk0 + 3][e] = v0.w;
                At[kk0 + 4][e] = v1.x; At[kk0 + 5][e] = v1.y;
                At[kk0 + 6][e] = v1.z; At[kk0 + 7][e] = v1.w;
            }
            __syncthreads();
#pragma unroll
            for (int kk = 0; kk < KCH; ++kk) {
                float4 a = *(const float4*)&At[kk][e0];
                float4 w = *(const float4*)&w1s[c * 32 + kk][j0];
                acc[0].x += a.x * w.x; acc[0].y += a.y * w.x; acc[0].z += a.z * w.x; acc[0].w += a.w * w.x;
                acc[1].x += a.x * w.y; acc[1].y += a.y * w.y; acc[1].z += a.z * w.y; acc[1].w += a.w * w.y;
                acc[2].x += a.x * w.z; acc[2].y += a.y * w.z; acc[2].z += a.z * w.z; acc[2].w += a.w * w.z;
                acc[3].x += a.x * w.w; acc[3].y += a.y * w.w; acc[3].z += a.z * w.w; acc[3].w += a.w * w.w;
            }
        }

#pragma unroll
        for (int ji = 0; ji < 4; ++ji) {
            float4 r;
            r.x = reluf(acc[ji].x); r.y = reluf(acc[ji].y);
            r.z = reluf(acc[ji].z); r.w = reluf(acc[ji].w);
            *(float4*)&m1t[j0 + ji][e0] = r;
        }
        __syncthreads();

        float4 o[4];
#pragma unroll
        for (int ji = 0; ji < 4; ++ji) {
            float bv = b2s[j0 + ji];
            o[ji] = make_float4(bv, bv, bv, bv);
        }
#pragma unroll 16
        for (int k = 0; k < EMB; ++k) {
            float4 a = *(const float4*)&m1t[k][e0];
            float4 w = *(const float4*)&w2s[k][j0];
            o[0].x += a.x * w.x; o[0].y += a.y * w.x; o[0].z += a.z * w.x; o[0].w += a.w * w.x;
            o[1].x += a.x * w.y; o[1].y += a.y * w.y; o[1].z += a.z * w.y; o[1].w += a.w * w.y;
            o[2].x += a.x * w.z; o[2].y += a.y * w.z; o[2].z += a.z * w.z; o[2].w += a.w * w.z;
            o[3].x += a.x * w.w; o[3].y += a.y * w.w; o[3].z += a.z * w.w; o[3].w += a.w * w.w;
        }

        // residual add: h[n][j0..j0+3] += relu(u2)
#pragma unroll
        for (int ei = 0; ei < 4; ++ei) {
            int n = t0 + e0 + ei;
            if (n < N) {
                float4* hp = (float4*)&h[(size_t)n * EMB + j0];
                float4 cur = *hp;
                cur.x += reluf(f4c(o[0], ei));
                cur.y += reluf(f4c(o[1], ei));
                cur.z += reluf(f4c(o[2], ei));
                cur.w += reluf(f4c(o[3], ei));
                *hp = cur;
            }
        }

        // re-zero this tile's aggr rows (last read was in staging chunks c=2,3;
        // only this block touches rows [t0, t0+TILE) — no cross-block hazard)
        {
            const int zr = t0 + (tid >> 2);
            if (zr < N) {
                float4 z = make_float4(0.f, 0.f, 0.f, 0.f);
                float4* zp = (float4*)&aggr[(size_t)zr * EMB + (tid & 3) * 16];
                zp[0] = z; zp[1] = z; zp[2] = z; zp[3] = z;
            }
        }
        __syncthreads();  // m1t/At reuse safety for next tile
    }
}

// --------------------------------------------------------------- pooling ----
__global__ __launch_bounds__(256) void pool_kernel(
    const float* __restrict__ h, float* __restrict__ pool, int N)
{
    __shared__ float red[4][EMB];
    const int lane = threadIdx.x & 63;
    const int wv = threadIdx.x >> 6;
    float s = 0.0f;
    for (int n = blockIdx.x * 4 + wv; n < N; n += gridDim.x * 4)
        s += h[(size_t)n * EMB + lane];
    red[wv][lane] = s;
    __syncthreads();
    if (threadIdx.x < EMB) {
        float t = red[0][threadIdx.x] + red[1][threadIdx.x] +
                  red[2][threadIdx.x] + red[3][threadIdx.x];
        atomicAdd(&pool[threadIdx.x], t);
    }
}

__global__ void final_kernel(const float* __restrict__ pool,
                             const float* __restrict__ pw,
                             const float* __restrict__ pb,
                             float* __restrict__ out, int N)
{
    int j = threadIdx.x;  // 64 threads
    float v = (pool[j] / (float)N) * pw[j];
#pragma unroll
    for (int off = 32; off; off >>= 1) v += __shfl_down(v, off, 64);
    if (j == 0) out[0] = v + pb[0];
}

// ---------------------------------------------------------------- launch ----
extern "C" void kernel_launch(void* const* d_in, const int* in_sizes, int n_in,
                              void* d_out, int out_size, void* d_ws, size_t ws_size,
                              hipStream_t stream)
{
    const float* x     = (const float*)d_in[0];
    const float* dists = (const float*)d_in[1];
    const int*   ei    = (const int*)d_in[2];
    // d_in[3] = batch (all zeros, unused: single graph mean pool)
    const float* lw  = (const float*)d_in[4];
    const float* lb  = (const float*)d_in[5];
    const float* mw1 = (const float*)d_in[6];
    const float* mb1 = (const float*)d_in[7];
    const float* mw2 = (const float*)d_in[8];
    const float* mb2 = (const float*)d_in[9];
    const float* uw1 = (const float*)d_in[10];
    const float* ub1 = (const float*)d_in[11];
    const float* uw2 = (const float*)d_in[12];
    const float* ub2 = (const float*)d_in[13];
    const float* pw  = (const float*)d_in[14];
    const float* pb  = (const float*)d_in[15];

    const int N = in_sizes[0] / 5;
    const int E = in_sizes[2] / 2;
    const int* src = ei;        // edge_index[0]
    const int* dst = ei + E;    // edge_index[1]

    // Workspace layout:
    //   h [N*EMB] f32 | aggr [N*EMB] f32 | pool [EMB] f32 |
    //   cnt [N] i32 | cursor [N] i32 | bsum [256] i32 | perm [E] i32
    const size_t need = ((size_t)N * EMB * 2 + EMB) * sizeof(float)
                      + ((size_t)2 * N + 256 + (size_t)E) * sizeof(int);
    const int nchunk = (N + SCAN_CHUNK - 1) / SCAN_CHUNK;  // scan2 handles <=256
    if (ws_size < need || nchunk > 256) {
        return;  // defensive: clean wrong-answer instead of OOB scribble
    }

    float* h    = (float*)d_ws;
    float* aggr = h + (size_t)N * EMB;
    float* pool = aggr + (size_t)N * EMB;
    int* cnt    = (int*)(pool + EMB);
    int* cursor = cnt + N;
    int* bsum   = cursor + N;
    int* perm   = bsum + 256;

    // ---- CSR build: counting sort of edges by dst ----
    hipMemsetAsync(cnt, 0, (size_t)N * sizeof(int), stream);
    int hgrid = (E + 255) / 256; if (hgrid > 2048) hgrid = 2048;
    hist_kernel<<<hgrid, 256, 0, stream>>>(dst, cnt, E);
    scan1_kernel<<<nchunk, 256, 0, stream>>>(cnt, cursor, bsum, N);
    scan2_kernel<<<1, 256, 0, stream>>>(bsum, nchunk);
    int sgrid = (N + 255) / 256; if (sgrid > 512) sgrid = 512;
    scan3_kernel<<<sgrid, 256, 0, stream>>>(cursor, bsum, N);
    scatter_kernel<<<hgrid, 256, 0, stream>>>(dst, cursor, perm, E);

    lin_in_kernel<<<(N * EMB + THREADS - 1) / THREADS, THREADS, 0, stream>>>(x, lw, lb, h, N);

    // 2 blocks/CU (LDS-limited) x 256 CUs = 512 co-resident blocks
    int egrid = 512;
    int etiles = (E + TILE - 1) / TILE;
    if (etiles < egrid) egrid = etiles;
    int ugrid = 512;
    int utiles = (N + TILE - 1) / TILE;
    if (utiles < ugrid) ugrid = utiles;

    // aggr must start zeroed (ws is poisoned 0xAA before every launch);
    // node_upd_kernel re-zeroes it for subsequent layers.
    hipMemsetAsync(aggr, 0, (size_t)N * EMB * sizeof(float), stream);

    for (int l = 0; l < 4; ++l) {
        edge_msg_kernel<<<egrid, THREADS, 0, stream>>>(
            h, dists, src, dst, perm,
            mw1 + (size_t)l * 129 * EMB, mb1 + l * EMB,
            mw2 + (size_t)l * EMB * EMB, mb2 + l * EMB,
            aggr, E);
        node_upd_kernel<<<ugrid, THREADS, 0, stream>>>(
            h, aggr,
            uw1 + (size_t)l * 128 * EMB, ub1 + l * EMB,
            uw2 + (size_t)l * EMB * EMB, ub2 + l * EMB, N);
    }

    hipMemsetAsync(pool, 0, EMB * sizeof(float), stream);
    pool_kernel<<<256, 256, 0, stream>>>(h, pool, N);
    final_kernel<<<1, 64, 0, stream>>>(pool, pw, pb, (float*)d_out, N);
}